// Round 1
// baseline (344.795 us; speedup 1.0000x reference)
//
#include <hip/hip_runtime.h>

#define NN 50000
#define DD 64
#define EE 800000

// ---------------------------------------------------------------------------
// Kernel 1: x[i][j] = sum_k nf[i][k] * W[j][k] + b_lin[j]
// One wave per node row. W staged in LDS with stride-65 padding:
// lane j reads Wsh[j*65+k] -> bank (j+k)%32, conflict-free across the wave.
// nf row held one element per lane, broadcast via __shfl.
// ---------------------------------------------------------------------------
__global__ __launch_bounds__(256) void linear_kernel(
    const float* __restrict__ nf, const float* __restrict__ W,
    const float* __restrict__ b_lin, float* __restrict__ x) {
  __shared__ float Wsh[64 * 65];
  int tid = threadIdx.x;
#pragma unroll
  for (int s = 0; s < 16; ++s) {
    int idx = s * 256 + tid;
    int j = idx >> 6, k = idx & 63;
    Wsh[j * 65 + k] = W[idx];
  }
  __syncthreads();

  int lane = tid & 63;
  int wave = tid >> 6;
  int i = blockIdx.x * 4 + wave;
  if (i >= NN) return;

  float nfj = nf[i * DD + lane];
  float acc = b_lin[lane];
#pragma unroll
  for (int k = 0; k < 64; ++k) {
    float a = __shfl(nfj, k, 64);
    acc = fmaf(a, Wsh[lane * 65 + k], acc);
  }
  x[i * DD + lane] = acc;
}

// ---------------------------------------------------------------------------
// Kernel 2: scatter-add aggregation. One wave per edge; lane j handles
// feature j. agg lives in d_out (zeroed before launch). Degree in fp32.
// ---------------------------------------------------------------------------
__global__ __launch_bounds__(256) void edge_agg_kernel(
    const float* __restrict__ x, const int* __restrict__ ei,
    float* __restrict__ agg, float* __restrict__ deg) {
  int e = blockIdx.x * 4 + (threadIdx.x >> 6);
  int lane = threadIdx.x & 63;
  if (e >= EE) return;
  int src = ei[2 * e];
  int dst = ei[2 * e + 1];
  float v = x[src * DD + lane];
  atomicAdd(&agg[dst * DD + lane], v);
  if (lane == 0) atomicAdd(&deg[dst], 1.0f);
}

// ---------------------------------------------------------------------------
// Kernel 3: out = relu(x + agg/max(deg,1) + bias), float4-vectorized.
// agg aliases out; each thread RMWs only its own 16B, so in-place is safe.
// ---------------------------------------------------------------------------
__global__ __launch_bounds__(256) void finalize_kernel(
    const float* __restrict__ x, const float* __restrict__ deg,
    const float* __restrict__ bias, float* __restrict__ out) {
  int idx = blockIdx.x * blockDim.x + threadIdx.x;
  int g = idx * 4;
  if (g >= NN * DD) return;
  int i = g >> 6;
  int j = g & 63;
  float d = fmaxf(deg[i], 1.0f);
  float inv = 1.0f / d;
  float4 xv = *(const float4*)(x + g);
  float4 av = *(const float4*)(out + g);
  float4 bv = *(const float4*)(bias + j);
  float4 o;
  o.x = fmaxf(fmaf(av.x, inv, xv.x) + bv.x, 0.0f);
  o.y = fmaxf(fmaf(av.y, inv, xv.y) + bv.y, 0.0f);
  o.z = fmaxf(fmaf(av.z, inv, xv.z) + bv.z, 0.0f);
  o.w = fmaxf(fmaf(av.w, inv, xv.w) + bv.w, 0.0f);
  *(float4*)(out + g) = o;
}

extern "C" void kernel_launch(void* const* d_in, const int* in_sizes, int n_in,
                              void* d_out, int out_size, void* d_ws, size_t ws_size,
                              hipStream_t stream) {
  const float* nf    = (const float*)d_in[0];   // (N, D) fp32
  const int*   ei    = (const int*)d_in[1];     // (E, 2) int (harness delivers int32)
  const float* W     = (const float*)d_in[2];   // (D, D) fp32
  const float* b_lin = (const float*)d_in[3];   // (D,)  fp32
  const float* bias  = (const float*)d_in[4];   // (D,)  fp32
  float* out = (float*)d_out;                   // (N, D) fp32; doubles as agg buffer

  float* x   = (float*)d_ws;                    // N*D floats
  float* deg = x + (size_t)NN * DD;             // N floats
  // ws usage: (N*D + N)*4 = 13.0 MB

  hipMemsetAsync(out, 0, (size_t)NN * DD * sizeof(float), stream);
  hipMemsetAsync(deg, 0, (size_t)NN * sizeof(float), stream);

  linear_kernel<<<(NN + 3) / 4, 256, 0, stream>>>(nf, W, b_lin, x);
  edge_agg_kernel<<<(EE + 3) / 4, 256, 0, stream>>>(x, ei, out, deg);
  finalize_kernel<<<(NN * DD / 4 + 255) / 256, 256, 0, stream>>>(x, deg, bias, out);
}

// Round 2
// 262.058 us; speedup vs baseline: 1.3157x; 1.3157x over previous
//
#include <hip/hip_runtime.h>

#define NN 50000
#define DD 64
#define EE 800000
#define NB 196  // (NN+255)/256 scan blocks

// ---------------------------------------------------------------------------
// Kernel 1: x[i][j] = sum_k nf[i][k] * W[j][k] + b_lin[j]
// One wave per node row; W in LDS with stride-65 padding (conflict-free).
// ---------------------------------------------------------------------------
__global__ __launch_bounds__(256) void linear_kernel(
    const float* __restrict__ nf, const float* __restrict__ W,
    const float* __restrict__ b_lin, float* __restrict__ x) {
  __shared__ float Wsh[64 * 65];
  int tid = threadIdx.x;
#pragma unroll
  for (int s = 0; s < 16; ++s) {
    int idx = s * 256 + tid;
    int j = idx >> 6, k = idx & 63;
    Wsh[j * 65 + k] = W[idx];
  }
  __syncthreads();

  int lane = tid & 63;
  int i = blockIdx.x * 4 + (tid >> 6);
  if (i >= NN) return;

  float nfj = nf[i * DD + lane];
  float acc = b_lin[lane];
#pragma unroll
  for (int k = 0; k < 64; ++k) {
    float a = __shfl(nfj, k, 64);
    acc = fmaf(a, Wsh[lane * 65 + k], acc);
  }
  x[i * DD + lane] = acc;
}

// ---------------------------------------------------------------------------
// CSR build: histogram -> exclusive scan (3 kernels) -> scatter
// ---------------------------------------------------------------------------
__global__ __launch_bounds__(256) void hist_kernel(
    const int* __restrict__ ei, int* __restrict__ cnt) {
  int e = blockIdx.x * 256 + threadIdx.x;
  if (e >= EE) return;
  atomicAdd(&cnt[ei[2 * e + 1]], 1);
}

__global__ __launch_bounds__(256) void scan1_kernel(
    const int* __restrict__ cnt, int* __restrict__ partial) {
  __shared__ int s[256];
  int t = threadIdx.x;
  int i = blockIdx.x * 256 + t;
  s[t] = (i < NN) ? cnt[i] : 0;
  __syncthreads();
#pragma unroll
  for (int o = 128; o > 0; o >>= 1) {
    if (t < o) s[t] += s[t + o];
    __syncthreads();
  }
  if (t == 0) partial[blockIdx.x] = s[0];
}

__global__ __launch_bounds__(256) void scan2_kernel(int* __restrict__ partial) {
  __shared__ int s[256];
  int t = threadIdx.x;
  int v = (t < NB) ? partial[t] : 0;
  s[t] = v;
  __syncthreads();
#pragma unroll
  for (int o = 1; o < 256; o <<= 1) {
    int u = (t >= o) ? s[t - o] : 0;
    __syncthreads();
    s[t] += u;
    __syncthreads();
  }
  if (t < NB) partial[t] = s[t] - v;  // exclusive
}

__global__ __launch_bounds__(256) void scan3_kernel(
    const int* __restrict__ cnt, const int* __restrict__ partial,
    int* __restrict__ csr_off, int* __restrict__ cur) {
  __shared__ int s[256];
  int t = threadIdx.x;
  int i = blockIdx.x * 256 + t;
  int v = (i < NN) ? cnt[i] : 0;
  s[t] = v;
  __syncthreads();
#pragma unroll
  for (int o = 1; o < 256; o <<= 1) {
    int u = (t >= o) ? s[t - o] : 0;
    __syncthreads();
    s[t] += u;
    __syncthreads();
  }
  int off = partial[blockIdx.x] + s[t] - v;  // exclusive scan of cnt
  if (i < NN) {
    csr_off[i] = off;
    cur[i] = off;
    if (i == NN - 1) csr_off[NN] = off + v;  // == EE
  }
}

__global__ __launch_bounds__(256) void scatter_kernel(
    const int* __restrict__ ei, int* __restrict__ cur,
    int* __restrict__ csr_src) {
  int e = blockIdx.x * 256 + threadIdx.x;
  if (e >= EE) return;
  int src = ei[2 * e];
  int dst = ei[2 * e + 1];
  int pos = atomicAdd(&cur[dst], 1);
  csr_src[pos] = src;
}

// ---------------------------------------------------------------------------
// Fused gather + finalize: one wave per node, lane j = feature j.
// Each edge iteration reads one contiguous 256 B row of x (L2/L3-resident).
// out = relu(x + acc/max(deg,1) + bias), written once, no atomics.
// ---------------------------------------------------------------------------
__global__ __launch_bounds__(256) void gather_kernel(
    const float* __restrict__ x, const int* __restrict__ csr_src,
    const int* __restrict__ csr_off, const float* __restrict__ bias,
    float* __restrict__ out) {
  int i = blockIdx.x * 4 + (threadIdx.x >> 6);
  int j = threadIdx.x & 63;
  if (i >= NN) return;
  int beg = csr_off[i];
  int end = csr_off[i + 1];
  float acc = 0.0f;
  int k = beg;
  for (; k + 4 <= end; k += 4) {  // 4 independent row-reads in flight
    int s0 = csr_src[k], s1 = csr_src[k + 1];
    int s2 = csr_src[k + 2], s3 = csr_src[k + 3];
    float v0 = x[s0 * DD + j], v1 = x[s1 * DD + j];
    float v2 = x[s2 * DD + j], v3 = x[s3 * DD + j];
    acc += (v0 + v1) + (v2 + v3);
  }
  for (; k < end; ++k) acc += x[csr_src[k] * DD + j];
  float deg = (float)(end - beg);
  float inv = 1.0f / fmaxf(deg, 1.0f);
  out[i * DD + j] = fmaxf(fmaf(acc, inv, x[i * DD + j] + bias[j]), 0.0f);
}

extern "C" void kernel_launch(void* const* d_in, const int* in_sizes, int n_in,
                              void* d_out, int out_size, void* d_ws, size_t ws_size,
                              hipStream_t stream) {
  const float* nf    = (const float*)d_in[0];
  const int*   ei    = (const int*)d_in[1];
  const float* W     = (const float*)d_in[2];
  const float* b_lin = (const float*)d_in[3];
  const float* bias  = (const float*)d_in[4];
  float* out = (float*)d_out;

  // workspace layout
  float* x       = (float*)d_ws;                 // N*D floats   (12.8 MB)
  int*   csr_src = (int*)(x + (size_t)NN * DD);  // E ints       (3.2 MB)
  int*   csr_off = csr_src + EE;                 // N+1 ints
  int*   cur     = csr_off + (NN + 1);           // N ints
  int*   cnt     = cur + NN;                     // N ints
  int*   partial = cnt + NN;                     // NB ints
  // total ~16.6 MB

  hipMemsetAsync(cnt, 0, (size_t)NN * sizeof(int), stream);

  linear_kernel<<<(NN + 3) / 4, 256, 0, stream>>>(nf, W, b_lin, x);
  hist_kernel<<<(EE + 255) / 256, 256, 0, stream>>>(ei, cnt);
  scan1_kernel<<<NB, 256, 0, stream>>>(cnt, partial);
  scan2_kernel<<<1, 256, 0, stream>>>(partial);
  scan3_kernel<<<NB, 256, 0, stream>>>(cnt, partial, csr_off, cur);
  scatter_kernel<<<(EE + 255) / 256, 256, 0, stream>>>(ei, cur, csr_src);
  gather_kernel<<<(NN + 3) / 4, 256, 0, stream>>>(x, csr_src, csr_off, bias, out);
}

// Round 3
// 245.791 us; speedup vs baseline: 1.4028x; 1.0662x over previous
//
#include <hip/hip_runtime.h>
#include <hip/hip_bf16.h>

#define NN 50000
#define DD 64
#define EE 800000
#define NB 196  // ceil(NN/256) scan blocks

typedef unsigned short u16;
typedef unsigned int u32;

__device__ __forceinline__ float bf2f(u16 u) {
  u32 t = ((u32)u) << 16;
  return __builtin_bit_cast(float, t);
}
__device__ __forceinline__ u16 f2bf(float f) {
  // round-to-nearest-even bf16
  u32 b = __builtin_bit_cast(u32, f);
  u32 r = (b + 0x7FFF + ((b >> 16) & 1)) >> 16;
  return (u16)r;
}

// ---------------------------------------------------------------------------
// Kernel 1: x[i][j] = sum_k nf[i][k] * W[j][k] + b_lin[j], stored as bf16.
// One wave per node row; W in LDS with stride-65 padding (conflict-free).
// ---------------------------------------------------------------------------
__global__ __launch_bounds__(256) void linear_kernel(
    const float* __restrict__ nf, const float* __restrict__ W,
    const float* __restrict__ b_lin, u16* __restrict__ x16) {
  __shared__ float Wsh[64 * 65];
  int tid = threadIdx.x;
#pragma unroll
  for (int s = 0; s < 16; ++s) {
    int idx = s * 256 + tid;
    int j = idx >> 6, k = idx & 63;
    Wsh[j * 65 + k] = W[idx];
  }
  __syncthreads();

  int lane = tid & 63;
  int i = blockIdx.x * 4 + (tid >> 6);
  if (i >= NN) return;

  float nfj = nf[i * DD + lane];
  float acc = b_lin[lane];
#pragma unroll
  for (int k = 0; k < 64; ++k) {
    float a = __shfl(nfj, k, 64);
    acc = fmaf(a, Wsh[lane * 65 + k], acc);
  }
  x16[i * DD + lane] = f2bf(acc);
}

// ---------------------------------------------------------------------------
// CSR build: histogram -> exclusive scan (3 kernels) -> scatter (u16 src ids)
// ---------------------------------------------------------------------------
__global__ __launch_bounds__(256) void hist_kernel(
    const int* __restrict__ ei, int* __restrict__ cnt) {
  int t = blockIdx.x * 256 + threadIdx.x;  // handles 2 edges
  if (2 * t >= EE) return;
  int4 p = *(const int4*)(ei + 4 * t);  // (src0,dst0,src1,dst1)
  atomicAdd(&cnt[p.y], 1);
  atomicAdd(&cnt[p.w], 1);
}

__global__ __launch_bounds__(256) void scan1_kernel(
    const int* __restrict__ cnt, int* __restrict__ partial) {
  __shared__ int s[256];
  int t = threadIdx.x;
  int i = blockIdx.x * 256 + t;
  s[t] = (i < NN) ? cnt[i] : 0;
  __syncthreads();
#pragma unroll
  for (int o = 128; o > 0; o >>= 1) {
    if (t < o) s[t] += s[t + o];
    __syncthreads();
  }
  if (t == 0) partial[blockIdx.x] = s[0];
}

__global__ __launch_bounds__(256) void scan2_kernel(int* __restrict__ partial) {
  __shared__ int s[256];
  int t = threadIdx.x;
  int v = (t < NB) ? partial[t] : 0;
  s[t] = v;
  __syncthreads();
#pragma unroll
  for (int o = 1; o < 256; o <<= 1) {
    int u = (t >= o) ? s[t - o] : 0;
    __syncthreads();
    s[t] += u;
    __syncthreads();
  }
  if (t < NB) partial[t] = s[t] - v;  // exclusive
}

__global__ __launch_bounds__(256) void scan3_kernel(
    const int* __restrict__ cnt, const int* __restrict__ partial,
    int* __restrict__ csr_off, int* __restrict__ cur) {
  __shared__ int s[256];
  int t = threadIdx.x;
  int i = blockIdx.x * 256 + t;
  int v = (i < NN) ? cnt[i] : 0;
  s[t] = v;
  __syncthreads();
#pragma unroll
  for (int o = 1; o < 256; o <<= 1) {
    int u = (t >= o) ? s[t - o] : 0;
    __syncthreads();
    s[t] += u;
    __syncthreads();
  }
  int off = partial[blockIdx.x] + s[t] - v;  // exclusive scan of cnt
  if (i < NN) {
    csr_off[i] = off;
    cur[i] = off;
    if (i == NN - 1) csr_off[NN] = off + v;  // == EE
  }
}

__global__ __launch_bounds__(256) void scatter_kernel(
    const int* __restrict__ ei, int* __restrict__ cur,
    u16* __restrict__ csr_src) {
  int t = blockIdx.x * 256 + threadIdx.x;  // handles 2 edges
  if (2 * t >= EE) return;
  int4 p = *(const int4*)(ei + 4 * t);
  int pos0 = atomicAdd(&cur[p.y], 1);
  csr_src[pos0] = (u16)p.x;
  int pos1 = atomicAdd(&cur[p.w], 1);
  csr_src[pos1] = (u16)p.z;
}

// ---------------------------------------------------------------------------
// Fused gather + finalize: one wave per node, lane j = feature j.
// Each edge iteration reads one contiguous 128 B bf16 row of x.
// out = relu(x + acc/max(deg,1) + bias), written once, no atomics.
// ---------------------------------------------------------------------------
__global__ __launch_bounds__(256) void gather_kernel(
    const u16* __restrict__ x16, const u16* __restrict__ csr_src,
    const int* __restrict__ csr_off, const float* __restrict__ bias,
    float* __restrict__ out) {
  int i = blockIdx.x * 4 + (threadIdx.x >> 6);
  int j = threadIdx.x & 63;
  if (i >= NN) return;
  int beg = csr_off[i];
  int end = csr_off[i + 1];
  float acc = 0.0f;
  int k = beg;
  for (; k + 4 <= end; k += 4) {  // 4 independent row-reads in flight
    int s0 = csr_src[k], s1 = csr_src[k + 1];
    int s2 = csr_src[k + 2], s3 = csr_src[k + 3];
    float v0 = bf2f(x16[s0 * DD + j]);
    float v1 = bf2f(x16[s1 * DD + j]);
    float v2 = bf2f(x16[s2 * DD + j]);
    float v3 = bf2f(x16[s3 * DD + j]);
    acc += (v0 + v1) + (v2 + v3);
  }
  for (; k < end; ++k) acc += bf2f(x16[(int)csr_src[k] * DD + j]);
  float deg = (float)(end - beg);
  float inv = 1.0f / fmaxf(deg, 1.0f);
  float self = bf2f(x16[i * DD + j]);
  out[i * DD + j] = fmaxf(fmaf(acc, inv, self + bias[j]), 0.0f);
}

extern "C" void kernel_launch(void* const* d_in, const int* in_sizes, int n_in,
                              void* d_out, int out_size, void* d_ws, size_t ws_size,
                              hipStream_t stream) {
  const float* nf    = (const float*)d_in[0];
  const int*   ei    = (const int*)d_in[1];
  const float* W     = (const float*)d_in[2];
  const float* b_lin = (const float*)d_in[3];
  const float* bias  = (const float*)d_in[4];
  float* out = (float*)d_out;

  // workspace layout
  u16* x16     = (u16*)d_ws;                       // N*D bf16   (6.4 MB)
  u16* csr_src = x16 + (size_t)NN * DD;            // E u16      (1.6 MB)
  int* csr_off = (int*)(csr_src + EE);             // N+1 ints
  int* cur     = csr_off + (NN + 1);               // N ints
  int* cnt     = cur + NN;                         // N ints
  int* partial = cnt + NN;                         // NB ints
  // total ~8.6 MB

  hipMemsetAsync(cnt, 0, (size_t)NN * sizeof(int), stream);

  linear_kernel<<<(NN + 3) / 4, 256, 0, stream>>>(nf, W, b_lin, x16);
  hist_kernel<<<(EE / 2 + 255) / 256, 256, 0, stream>>>(ei, cnt);
  scan1_kernel<<<NB, 256, 0, stream>>>(cnt, partial);
  scan2_kernel<<<1, 256, 0, stream>>>(partial);
  scan3_kernel<<<NB, 256, 0, stream>>>(cnt, partial, csr_off, cur);
  scatter_kernel<<<(EE / 2 + 255) / 256, 256, 0, stream>>>(ei, cur, csr_src);
  gather_kernel<<<(NN + 3) / 4, 256, 0, stream>>>(x16, csr_src, csr_off, bias, out);
}

// Round 4
// 198.211 us; speedup vs baseline: 1.7395x; 1.2401x over previous
//
#include <hip/hip_runtime.h>
#include <hip/hip_bf16.h>

#define NN 50000
#define DD 64
#define EE 800000
#define NB 196     // ceil(NN/256) scan blocks
#define NTILE 3125 // NN/16 row tiles (exact)

typedef unsigned short u16;
typedef unsigned int u32;
typedef __attribute__((ext_vector_type(8))) short bf16x8;
typedef __attribute__((ext_vector_type(4))) float f32x4;

__device__ __forceinline__ float bf2f(u16 u) {
  u32 t = ((u32)u) << 16;
  return __builtin_bit_cast(float, t);
}
__device__ __forceinline__ u16 f2bf(float f) {
  // round-to-nearest-even bf16
  u32 b = __builtin_bit_cast(u32, f);
  u32 r = (b + 0x7FFF + ((b >> 16) & 1)) >> 16;
  return (u16)r;
}

// ---------------------------------------------------------------------------
// Kernel 1 (MFMA): x[i][j] = sum_k nf[i][k] * W[j][k] + b_lin[j], bf16 out.
// One wave per 16-row tile; M=16,N=64,K=64 via 4 col-tiles x 2 K-steps of
// mfma_f32_16x16x32_bf16. W staged in LDS as bf16, row stride 72 (pad).
//   A frag: lane holds nf[row=base+(lane&15)][k=(lane>>4)*8 + j + 32*ks]
//   B frag: lane holds W[n=c*16+(lane&15)][k=(lane>>4)*8 + j + 32*ks]
//   C/D:    col=lane&15, row=(lane>>4)*4+reg   [verified m89/m91]
// ---------------------------------------------------------------------------
__global__ __launch_bounds__(256) void linear_mfma_kernel(
    const float* __restrict__ nf, const float* __restrict__ W,
    const float* __restrict__ b_lin, u16* __restrict__ x16) {
  __shared__ u16 Wsh[64 * 72];
  int tid = threadIdx.x;
#pragma unroll
  for (int s = 0; s < 16; ++s) {
    int idx = s * 256 + tid;
    int j = idx >> 6, k = idx & 63;
    Wsh[j * 72 + k] = f2bf(W[idx]);
  }
  __syncthreads();

  int wave = tid >> 6;
  int lane = tid & 63;
  int tile = blockIdx.x * 4 + wave;
  if (tile >= NTILE) return;  // after the only barrier: safe

  int m = lane & 15;
  int quad = lane >> 4;
  int rowbase = tile * 16;

  // B fragments from LDS (reused across nothing here, but cheap b128 reads)
  bf16x8 bfrag[4][2];
#pragma unroll
  for (int c = 0; c < 4; ++c) {
#pragma unroll
    for (int ks = 0; ks < 2; ++ks) {
      const u16* p = &Wsh[(c * 16 + m) * 72 + ks * 32 + quad * 8];
      bfrag[c][ks] = *(const bf16x8*)p;
    }
  }

  // A fragments from global fp32, converted to bf16
  bf16x8 afrag[2];
#pragma unroll
  for (int ks = 0; ks < 2; ++ks) {
    const float* p = nf + (rowbase + m) * DD + ks * 32 + quad * 8;
    float4 lo = *(const float4*)p;
    float4 hi = *(const float4*)(p + 4);
    bf16x8 a;
    a[0] = (short)f2bf(lo.x); a[1] = (short)f2bf(lo.y);
    a[2] = (short)f2bf(lo.z); a[3] = (short)f2bf(lo.w);
    a[4] = (short)f2bf(hi.x); a[5] = (short)f2bf(hi.y);
    a[6] = (short)f2bf(hi.z); a[7] = (short)f2bf(hi.w);
    afrag[ks] = a;
  }

  f32x4 acc[4];
#pragma unroll
  for (int c = 0; c < 4; ++c) {
    acc[c][0] = 0.0f; acc[c][1] = 0.0f; acc[c][2] = 0.0f; acc[c][3] = 0.0f;
  }
#pragma unroll
  for (int c = 0; c < 4; ++c) {
    acc[c] = __builtin_amdgcn_mfma_f32_16x16x32_bf16(afrag[0], bfrag[c][0], acc[c], 0, 0, 0);
    acc[c] = __builtin_amdgcn_mfma_f32_16x16x32_bf16(afrag[1], bfrag[c][1], acc[c], 0, 0, 0);
  }

  // Epilogue: add b_lin, store bf16
#pragma unroll
  for (int c = 0; c < 4; ++c) {
    int gcol = c * 16 + m;
    float bl = b_lin[gcol];
#pragma unroll
    for (int r = 0; r < 4; ++r) {
      int grow = rowbase + quad * 4 + r;
      x16[grow * DD + gcol] = f2bf(acc[c][r] + bl);
    }
  }
}

// ---------------------------------------------------------------------------
// CSR build: histogram -> exclusive scan (3 kernels) -> scatter (u16 src ids)
// ---------------------------------------------------------------------------
__global__ __launch_bounds__(256) void hist_kernel(
    const int* __restrict__ ei, int* __restrict__ cnt) {
  int t = blockIdx.x * 256 + threadIdx.x;  // handles 2 edges
  if (2 * t >= EE) return;
  int4 p = *(const int4*)(ei + 4 * t);  // (src0,dst0,src1,dst1)
  atomicAdd(&cnt[p.y], 1);
  atomicAdd(&cnt[p.w], 1);
}

__global__ __launch_bounds__(256) void scan1_kernel(
    const int* __restrict__ cnt, int* __restrict__ partial) {
  __shared__ int s[256];
  int t = threadIdx.x;
  int i = blockIdx.x * 256 + t;
  s[t] = (i < NN) ? cnt[i] : 0;
  __syncthreads();
#pragma unroll
  for (int o = 128; o > 0; o >>= 1) {
    if (t < o) s[t] += s[t + o];
    __syncthreads();
  }
  if (t == 0) partial[blockIdx.x] = s[0];
}

__global__ __launch_bounds__(256) void scan2_kernel(int* __restrict__ partial) {
  __shared__ int s[256];
  int t = threadIdx.x;
  int v = (t < NB) ? partial[t] : 0;
  s[t] = v;
  __syncthreads();
#pragma unroll
  for (int o = 1; o < 256; o <<= 1) {
    int u = (t >= o) ? s[t - o] : 0;
    __syncthreads();
    s[t] += u;
    __syncthreads();
  }
  if (t < NB) partial[t] = s[t] - v;  // exclusive
}

__global__ __launch_bounds__(256) void scan3_kernel(
    const int* __restrict__ cnt, const int* __restrict__ partial,
    int* __restrict__ csr_off, int* __restrict__ cur) {
  __shared__ int s[256];
  int t = threadIdx.x;
  int i = blockIdx.x * 256 + t;
  int v = (i < NN) ? cnt[i] : 0;
  s[t] = v;
  __syncthreads();
#pragma unroll
  for (int o = 1; o < 256; o <<= 1) {
    int u = (t >= o) ? s[t - o] : 0;
    __syncthreads();
    s[t] += u;
    __syncthreads();
  }
  int off = partial[blockIdx.x] + s[t] - v;  // exclusive scan of cnt
  if (i < NN) {
    csr_off[i] = off;
    cur[i] = off;
    if (i == NN - 1) csr_off[NN] = off + v;  // == EE
  }
}

__global__ __launch_bounds__(256) void scatter_kernel(
    const int* __restrict__ ei, int* __restrict__ cur,
    u16* __restrict__ csr_src) {
  int t = blockIdx.x * 256 + threadIdx.x;  // handles 2 edges
  if (2 * t >= EE) return;
  int4 p = *(const int4*)(ei + 4 * t);
  int pos0 = atomicAdd(&cur[p.y], 1);
  csr_src[pos0] = (u16)p.x;
  int pos1 = atomicAdd(&cur[p.w], 1);
  csr_src[pos1] = (u16)p.z;
}

// ---------------------------------------------------------------------------
// Fused gather + finalize: one wave per node, lane j = feature j.
// out = relu(x + acc/max(deg,1) + bias), written once, no atomics.
// ---------------------------------------------------------------------------
__global__ __launch_bounds__(256) void gather_kernel(
    const u16* __restrict__ x16, const u16* __restrict__ csr_src,
    const int* __restrict__ csr_off, const float* __restrict__ bias,
    float* __restrict__ out) {
  int i = blockIdx.x * 4 + (threadIdx.x >> 6);
  int j = threadIdx.x & 63;
  if (i >= NN) return;
  int beg = csr_off[i];
  int end = csr_off[i + 1];
  float acc = 0.0f;
  int k = beg;
  for (; k + 4 <= end; k += 4) {  // 4 independent row-reads in flight
    int s0 = csr_src[k], s1 = csr_src[k + 1];
    int s2 = csr_src[k + 2], s3 = csr_src[k + 3];
    float v0 = bf2f(x16[s0 * DD + j]);
    float v1 = bf2f(x16[s1 * DD + j]);
    float v2 = bf2f(x16[s2 * DD + j]);
    float v3 = bf2f(x16[s3 * DD + j]);
    acc += (v0 + v1) + (v2 + v3);
  }
  for (; k < end; ++k) acc += bf2f(x16[(int)csr_src[k] * DD + j]);
  float deg = (float)(end - beg);
  float inv = 1.0f / fmaxf(deg, 1.0f);
  float self = bf2f(x16[i * DD + j]);
  out[i * DD + j] = fmaxf(fmaf(acc, inv, self + bias[j]), 0.0f);
}

extern "C" void kernel_launch(void* const* d_in, const int* in_sizes, int n_in,
                              void* d_out, int out_size, void* d_ws, size_t ws_size,
                              hipStream_t stream) {
  const float* nf    = (const float*)d_in[0];
  const int*   ei    = (const int*)d_in[1];
  const float* W     = (const float*)d_in[2];
  const float* b_lin = (const float*)d_in[3];
  const float* bias  = (const float*)d_in[4];
  float* out = (float*)d_out;

  // workspace layout
  u16* x16     = (u16*)d_ws;                       // N*D bf16   (6.4 MB)
  u16* csr_src = x16 + (size_t)NN * DD;            // E u16      (1.6 MB)
  int* csr_off = (int*)(csr_src + EE);             // N+1 ints
  int* cur     = csr_off + (NN + 1);               // N ints
  int* cnt     = cur + NN;                         // N ints
  int* partial = cnt + NN;                         // NB ints
  // total ~8.6 MB

  hipMemsetAsync(cnt, 0, (size_t)NN * sizeof(int), stream);

  linear_mfma_kernel<<<(NTILE + 3) / 4, 256, 0, stream>>>(nf, W, b_lin, x16);
  hist_kernel<<<(EE / 2 + 255) / 256, 256, 0, stream>>>(ei, cnt);
  scan1_kernel<<<NB, 256, 0, stream>>>(cnt, partial);
  scan2_kernel<<<1, 256, 0, stream>>>(partial);
  scan3_kernel<<<NB, 256, 0, stream>>>(cnt, partial, csr_off, cur);
  scatter_kernel<<<(EE / 2 + 255) / 256, 256, 0, stream>>>(ei, cur, csr_src);
  gather_kernel<<<(NN + 3) / 4, 256, 0, stream>>>(x16, csr_src, csr_off, bias, out);
}

// Round 5
// 180.495 us; speedup vs baseline: 1.9103x; 1.0981x over previous
//
#include <hip/hip_runtime.h>
#include <hip/hip_bf16.h>

#define NN 50000
#define DD 64
#define EE 800000
#define NB 196      // ceil(NN/256) scan blocks
#define NTILE 3125  // NN/16 row tiles (exact)
#define NSLICE 128  // edge slices for scatter
#define ESL 6250    // EE/NSLICE edges per slice
#define DRNG 6250   // NN/8 dst nodes per XCD range

typedef unsigned short u16;
typedef unsigned int u32;
typedef __attribute__((ext_vector_type(8))) short bf16x8;
typedef __attribute__((ext_vector_type(4))) float f32x4;

__device__ __forceinline__ float bf2f(u16 u) {
  u32 t = ((u32)u) << 16;
  return __builtin_bit_cast(float, t);
}
__device__ __forceinline__ u16 f2bf(float f) {
  u32 b = __builtin_bit_cast(u32, f);
  u32 r = (b + 0x7FFF + ((b >> 16) & 1)) >> 16;
  return (u16)r;
}

// ---------------------------------------------------------------------------
// Kernel 1 (MFMA): x = nf @ W.T + b_lin, bf16 out. Also zeroes cnt[].
// One wave per 16-row tile; 4 col-tiles x 2 K-steps of mfma 16x16x32 bf16.
// C/D mapping: col=lane&15, row=(lane>>4)*4+reg  [verified m89/m91]
// ---------------------------------------------------------------------------
__global__ __launch_bounds__(256) void linear_mfma_kernel(
    const float* __restrict__ nf, const float* __restrict__ W,
    const float* __restrict__ b_lin, u16* __restrict__ x16,
    int* __restrict__ cnt) {
  __shared__ u16 Wsh[64 * 72];
  int tid = threadIdx.x;

  // fold hist-counter zeroing into this dispatch (completes before hist runs)
  if (blockIdx.x < NB) {
    int zi = blockIdx.x * 256 + tid;
    if (zi < NN) cnt[zi] = 0;
  }

#pragma unroll
  for (int s = 0; s < 16; ++s) {
    int idx = s * 256 + tid;
    int j = idx >> 6, k = idx & 63;
    Wsh[j * 72 + k] = f2bf(W[idx]);
  }
  __syncthreads();

  int wave = tid >> 6;
  int lane = tid & 63;
  int tile = blockIdx.x * 4 + wave;
  if (tile >= NTILE) return;  // after the only barrier: safe

  int m = lane & 15;
  int quad = lane >> 4;
  int rowbase = tile * 16;

  bf16x8 bfrag[4][2];
#pragma unroll
  for (int c = 0; c < 4; ++c) {
#pragma unroll
    for (int ks = 0; ks < 2; ++ks) {
      const u16* p = &Wsh[(c * 16 + m) * 72 + ks * 32 + quad * 8];
      bfrag[c][ks] = *(const bf16x8*)p;
    }
  }

  bf16x8 afrag[2];
#pragma unroll
  for (int ks = 0; ks < 2; ++ks) {
    const float* p = nf + (rowbase + m) * DD + ks * 32 + quad * 8;
    float4 lo = *(const float4*)p;
    float4 hi = *(const float4*)(p + 4);
    bf16x8 a;
    a[0] = (short)f2bf(lo.x); a[1] = (short)f2bf(lo.y);
    a[2] = (short)f2bf(lo.z); a[3] = (short)f2bf(lo.w);
    a[4] = (short)f2bf(hi.x); a[5] = (short)f2bf(hi.y);
    a[6] = (short)f2bf(hi.z); a[7] = (short)f2bf(hi.w);
    afrag[ks] = a;
  }

  f32x4 acc[4];
#pragma unroll
  for (int c = 0; c < 4; ++c) {
    acc[c][0] = 0.0f; acc[c][1] = 0.0f; acc[c][2] = 0.0f; acc[c][3] = 0.0f;
  }
#pragma unroll
  for (int c = 0; c < 4; ++c) {
    acc[c] = __builtin_amdgcn_mfma_f32_16x16x32_bf16(afrag[0], bfrag[c][0], acc[c], 0, 0, 0);
    acc[c] = __builtin_amdgcn_mfma_f32_16x16x32_bf16(afrag[1], bfrag[c][1], acc[c], 0, 0, 0);
  }

#pragma unroll
  for (int c = 0; c < 4; ++c) {
    int gcol = c * 16 + m;
    float bl = b_lin[gcol];
#pragma unroll
    for (int r = 0; r < 4; ++r) {
      int grow = rowbase + quad * 4 + r;
      x16[grow * DD + gcol] = f2bf(acc[c][r] + bl);
    }
  }
}

// ---------------------------------------------------------------------------
// hist: 4 edges per thread (two int4 loads), atomic per-dst counts.
// ---------------------------------------------------------------------------
__global__ __launch_bounds__(256) void hist_kernel(
    const int* __restrict__ ei, int* __restrict__ cnt) {
  int e = (blockIdx.x * 256 + threadIdx.x) * 4;
  if (e >= EE) return;
  int4 a = *(const int4*)(ei + 2 * e);
  int4 b = *(const int4*)(ei + 2 * e + 4);
  atomicAdd(&cnt[a.y], 1);
  atomicAdd(&cnt[a.w], 1);
  atomicAdd(&cnt[b.y], 1);
  atomicAdd(&cnt[b.w], 1);
}

// ---------------------------------------------------------------------------
// scan1: per-block sums of cnt -> partial[196]
// ---------------------------------------------------------------------------
__global__ __launch_bounds__(256) void scan1_kernel(
    const int* __restrict__ cnt, int* __restrict__ partial) {
  __shared__ int s[256];
  int t = threadIdx.x;
  int i = blockIdx.x * 256 + t;
  s[t] = (i < NN) ? cnt[i] : 0;
  __syncthreads();
#pragma unroll
  for (int o = 128; o > 0; o >>= 1) {
    if (t < o) s[t] += s[t + o];
    __syncthreads();
  }
  if (t == 0) partial[blockIdx.x] = s[0];
}

// ---------------------------------------------------------------------------
// scan23: each block redundantly scans partial[], then scans its cnt chunk.
// Writes csr_off (exclusive) and cur (= csr_off copy).
// ---------------------------------------------------------------------------
__global__ __launch_bounds__(256) void scan23_kernel(
    const int* __restrict__ cnt, const int* __restrict__ partial,
    int* __restrict__ csr_off, int* __restrict__ cur) {
  __shared__ int sp[256];
  __shared__ int s[256];
  __shared__ int boff;
  int t = threadIdx.x;

  int pv = (t < NB) ? partial[t] : 0;
  sp[t] = pv;
  __syncthreads();
#pragma unroll
  for (int o = 1; o < 256; o <<= 1) {
    int u = (t >= o) ? sp[t - o] : 0;
    __syncthreads();
    sp[t] += u;
    __syncthreads();
  }
  if (t == 0) boff = (blockIdx.x > 0) ? sp[blockIdx.x - 1] : 0;  // exclusive
  __syncthreads();

  int i = blockIdx.x * 256 + t;
  int v = (i < NN) ? cnt[i] : 0;
  s[t] = v;
  __syncthreads();
#pragma unroll
  for (int o = 1; o < 256; o <<= 1) {
    int u = (t >= o) ? s[t - o] : 0;
    __syncthreads();
    s[t] += u;
    __syncthreads();
  }
  int off = boff + s[t] - v;  // exclusive scan of cnt
  if (i < NN) {
    csr_off[i] = off;
    cur[i] = off;
    if (i == NN - 1) csr_off[NN] = off + v;  // == EE
  }
}

// ---------------------------------------------------------------------------
// scatter: XCD-sliced. Block b: dst range r=b&7 (6250 nodes), edge slice
// s=b>>3 (6250 edges). Each block reads its whole slice (8x read amp, cheap)
// but only claims/writes edges whose dst is in its range -> csr_src region
// and cur counters for a range are written by one XCD's L2 (round-robin
// heuristic; correctness independent of actual mapping).
// ---------------------------------------------------------------------------
__global__ __launch_bounds__(256) void scatter_kernel(
    const int* __restrict__ ei, int* __restrict__ cur,
    u16* __restrict__ csr_src) {
  int r = blockIdx.x & 7;
  int sl = blockIdx.x >> 3;
  int rlo = r * DRNG;
  int ebase = sl * ESL;
  int eend = ebase + ESL;
#pragma unroll 1
  for (int it = 0; it < 13; ++it) {
    int e = ebase + it * 512 + (int)threadIdx.x * 2;
    if (e < eend) {
      int4 p = *(const int4*)(ei + 2 * e);  // (src0,dst0,src1,dst1)
      if ((u32)(p.y - rlo) < (u32)DRNG) {
        int pos = atomicAdd(&cur[p.y], 1);
        csr_src[pos] = (u16)p.x;
      }
      if ((u32)(p.w - rlo) < (u32)DRNG) {
        int pos = atomicAdd(&cur[p.w], 1);
        csr_src[pos] = (u16)p.z;
      }
    }
  }
}

// ---------------------------------------------------------------------------
// gather: one wave per node. Index prefetch: one coalesced 128 B load grabs
// 64 csr_src entries; readlane broadcasts each to SGPR so all row loads
// issue independently (MLP = deg, not 4). Lanes >= deg hold garbage indices;
// their rows stay inside d_ws (u16 max -> 8.4 MB < 256 MiB) and their
// contribution is cndmask-gated to 0 (NaN-safe: select, not multiply).
// ---------------------------------------------------------------------------
template <int BASE>
__device__ __forceinline__ float chunk16(int my, int n,
                                         const u16* __restrict__ x16, int j) {
  float v[16];
#pragma unroll
  for (int k = 0; k < 16; ++k) {
    int s = __builtin_amdgcn_readlane(my, BASE + k);
    v[k] = bf2f(x16[s * DD + j]);
  }
  float a = 0.0f;
#pragma unroll
  for (int k = 0; k < 16; ++k) a += (k < n) ? v[k] : 0.0f;
  return a;
}

__global__ __launch_bounds__(256) void gather_kernel(
    const u16* __restrict__ x16, const u16* __restrict__ csr_src,
    const int* __restrict__ csr_off, const float* __restrict__ bias,
    float* __restrict__ out) {
  int i = blockIdx.x * 4 + (threadIdx.x >> 6);  // grid exact: NN/4 blocks
  int j = threadIdx.x & 63;
  int beg = csr_off[i];
  int end = csr_off[i + 1];
  float acc = 0.0f;
  int pos = beg;
#pragma unroll 1
  while (pos < end) {  // wave-uniform; 1 iter for deg<=64 (always, in practice)
    int my = (int)csr_src[pos + j];  // csr_src padded by 64 entries
    int win = end - pos;
    win = win > 64 ? 64 : win;
    acc += chunk16<0>(my, win, x16, j);
    if (win > 16) acc += chunk16<16>(my, win - 16, x16, j);
    if (win > 32) acc += chunk16<32>(my, win - 32, x16, j);
    if (win > 48) acc += chunk16<48>(my, win - 48, x16, j);
    pos += 64;
  }
  float deg = (float)(end - beg);
  float inv = 1.0f / fmaxf(deg, 1.0f);
  float self = bf2f(x16[i * DD + j]);
  out[i * DD + j] = fmaxf(fmaf(acc, inv, self + bias[j]), 0.0f);
}

extern "C" void kernel_launch(void* const* d_in, const int* in_sizes, int n_in,
                              void* d_out, int out_size, void* d_ws, size_t ws_size,
                              hipStream_t stream) {
  const float* nf    = (const float*)d_in[0];
  const int*   ei    = (const int*)d_in[1];
  const float* W     = (const float*)d_in[2];
  const float* b_lin = (const float*)d_in[3];
  const float* bias  = (const float*)d_in[4];
  float* out = (float*)d_out;

  // workspace layout (x16 MUST be at base: gather's garbage-index reads land
  // in [0, 8.4 MB) of d_ws)
  u16* x16     = (u16*)d_ws;                       // N*D bf16   (6.4 MB)
  u16* csr_src = x16 + (size_t)NN * DD;            // E u16 + 64 pad (1.6 MB)
  int* csr_off = (int*)(csr_src + EE + 64);        // N+1 ints
  int* cur     = csr_off + (NN + 1);               // N ints
  int* cnt     = cur + NN;                         // N ints
  int* partial = cnt + NN;                         // NB ints
  // total ~8.6 MB << ws_size

  linear_mfma_kernel<<<(NTILE + 3) / 4, 256, 0, stream>>>(nf, W, b_lin, x16, cnt);
  hist_kernel<<<(EE / 4 + 255) / 256, 256, 0, stream>>>(ei, cnt);
  scan1_kernel<<<NB, 256, 0, stream>>>(cnt, partial);
  scan23_kernel<<<NB, 256, 0, stream>>>(cnt, partial, csr_off, cur);
  scatter_kernel<<<NSLICE * 8, 256, 0, stream>>>(ei, cur, csr_src);
  gather_kernel<<<NN / 4, 256, 0, stream>>>(x16, csr_src, csr_off, bias, out);
}